// Round 10
// baseline (29317.484 us; speedup 1.0000x reference)
//
#include <hip/hip_runtime.h>

#define HIDDEN  100
#define SEQLEN  65536
#define XTILE   256
#define NT      512   // 8 waves, 2 per SIMD

typedef float    f32x2v __attribute__((ext_vector_type(2)));
typedef _Float16 h16x2 __attribute__((ext_vector_type(2)));

#define DPP_XOR1 0xB1  // quad_perm [1,0,3,2]
#define DPP_XOR2 0x4E  // quad_perm [2,3,0,1]
#define DPP_BC0  0x00  // quad_perm [0,0,0,0]
#define DPP_BC1  0x55  // quad_perm [1,1,1,1]
#define DPP_BC2  0xAA  // quad_perm [2,2,2,2]
#define DPP_BC3  0xFF  // quad_perm [3,3,3,3]

#if defined(__has_builtin) && __has_builtin(__builtin_amdgcn_rcpf)
#define RCPF(x) __builtin_amdgcn_rcpf(x)
#else
#define RCPF(x) (1.0f / (x))
#endif

#define QP(v, ctrl) __int_as_float(__builtin_amdgcn_mov_dpp(__float_as_int(v), (ctrl), 0xf, 0xf, true))

static __device__ __forceinline__ h16x2 as_h2(unsigned u) {
    union { unsigned u; h16x2 h; } cv; cv.u = u; return cv.h;
}
static __device__ __forceinline__ float dot2(h16x2 a, h16x2 b, float c) {
#if defined(__has_builtin) && __has_builtin(__builtin_amdgcn_fdot2)
    return __builtin_amdgcn_fdot2(a, b, c, false);
#else
    return __builtin_fmaf((float)a.y, (float)b.y, __builtin_fmaf((float)a.x, (float)b.x, c));
#endif
}

// Lane QUAD owns hidden unit j = tid>>2. Role r = tid&3 computes the K-quarter
// k in [25r, 25r+25) for ALL FOUR gates (52 dot2, 13-deep chains), plus input
// element r of the W_ih part (bias on role 0). Two DPP-XOR merges give every
// lane full preacts; role r activates gate r (1 trans-pair/lane); 4 quad_perm
// broadcasts deliver i,f,g,o to all lanes; uniform redundant cell update.
// h LDS layout (f16): 4 regions of 32 f16 slots (16 dwords, 64B-aligned);
// region r slots 0..24 = h[25r..25r+24], slot 25 = 0 pad, rest unused.
__global__ __launch_bounds__(NT) __attribute__((amdgpu_waves_per_eu(2, 2)))
void lstm_seq9(const float* __restrict__ x,      // [SEQ][4]
               const float* __restrict__ W_ih,   // [400][4]
               const float* __restrict__ W_hh,   // [400][100]
               const float* __restrict__ b_ih,   // [400]
               const float* __restrict__ b_hh,   // [400]
               const float* __restrict__ W_lin,  // [1][100]
               const float* __restrict__ b_lin,  // [1]
               float* __restrict__ out)          // [1]
{
    __shared__ __align__(16) unsigned hbuf[2][64]; // 2 × 64 dwords (4 regions × 16)
    __shared__ __align__(16) float    xsf[XTILE * 4]; // staged x tile, [256][4] f32
    __shared__ float red[128];

    const int tid = threadIdx.x;
    const int j   = tid >> 2;        // hidden unit (active < 100)
    const int r   = tid & 3;         // K-quarter / gate role
    const bool active = (j < HIDDEN);
    const int jj  = active ? j : 0;
    const int off = r * 25;          // K offset for this lane

    // ---- per-lane weights: 4 gates × 25 k-values, packed f16x2 (13 dwords each) ----
    h16x2 w[4][13];
    float wx[4], bz[4];
#pragma unroll
    for (int g = 0; g < 4; ++g) {
        const int row = g * HIDDEN + jj;
        const float* wr = W_hh + row * HIDDEN + off;
#pragma unroll
        for (int q = 0; q < 12; ++q) {
            h16x2 pw; pw.x = (_Float16)wr[2*q]; pw.y = (_Float16)wr[2*q+1];
            w[g][q] = pw;
        }
        { h16x2 pw; pw.x = (_Float16)wr[24]; pw.y = (_Float16)0; w[g][12] = pw; }
        wx[g] = W_ih[row * 4 + r];                    // input element r
        bz[g] = (r == 0) ? (b_ih[row] + b_hh[row]) : 0.f;
    }
    const float mm  = (r == 2) ? 2.0f : 1.0f;   // gate g (role 2): tanh = 2*sig(2s)-1
    const float mm1 = mm - 1.0f;
    float c = 0.f;                              // redundant across the quad

    if (tid < 128) ((unsigned*)hbuf)[tid] = 0u;
    __syncthreads();

    const int wslot = 32 * (jj / 25) + (jj % 25);   // this unit's f16 slot

    auto step = [&](int rd, int wrb, int tt) {
        // h reads: my K-quarter region (3×b128 + 1×b32), same addr within role group
        const uint4* h4 = reinterpret_cast<const uint4*>(hbuf[rd] + 16 * r);
        const uint4 hv0 = h4[0], hv1 = h4[1], hv2 = h4[2];
        const unsigned hv3 = hbuf[rd][16 * r + 12];
        const float xe = xsf[tt * 4 + r];            // my input element

        float a0 = __builtin_fmaf(wx[0], xe, bz[0]);
        float a1 = __builtin_fmaf(wx[1], xe, bz[1]);
        float a2 = __builtin_fmaf(wx[2], xe, bz[2]);
        float a3 = __builtin_fmaf(wx[3], xe, bz[3]);

        {
            const h16x2 h0 = as_h2(hv0.x), h1 = as_h2(hv0.y);
            const h16x2 h2 = as_h2(hv0.z), h3 = as_h2(hv0.w);
            a0 = dot2(w[0][0], h0, a0); a1 = dot2(w[1][0], h0, a1);
            a2 = dot2(w[2][0], h0, a2); a3 = dot2(w[3][0], h0, a3);
            a0 = dot2(w[0][1], h1, a0); a1 = dot2(w[1][1], h1, a1);
            a2 = dot2(w[2][1], h1, a2); a3 = dot2(w[3][1], h1, a3);
            a0 = dot2(w[0][2], h2, a0); a1 = dot2(w[1][2], h2, a1);
            a2 = dot2(w[2][2], h2, a2); a3 = dot2(w[3][2], h2, a3);
            a0 = dot2(w[0][3], h3, a0); a1 = dot2(w[1][3], h3, a1);
            a2 = dot2(w[2][3], h3, a2); a3 = dot2(w[3][3], h3, a3);
        }
        {
            const h16x2 h0 = as_h2(hv1.x), h1 = as_h2(hv1.y);
            const h16x2 h2 = as_h2(hv1.z), h3 = as_h2(hv1.w);
            a0 = dot2(w[0][4], h0, a0); a1 = dot2(w[1][4], h0, a1);
            a2 = dot2(w[2][4], h0, a2); a3 = dot2(w[3][4], h0, a3);
            a0 = dot2(w[0][5], h1, a0); a1 = dot2(w[1][5], h1, a1);
            a2 = dot2(w[2][5], h1, a2); a3 = dot2(w[3][5], h1, a3);
            a0 = dot2(w[0][6], h2, a0); a1 = dot2(w[1][6], h2, a1);
            a2 = dot2(w[2][6], h2, a2); a3 = dot2(w[3][6], h2, a3);
            a0 = dot2(w[0][7], h3, a0); a1 = dot2(w[1][7], h3, a1);
            a2 = dot2(w[2][7], h3, a2); a3 = dot2(w[3][7], h3, a3);
        }
        {
            const h16x2 h0 = as_h2(hv2.x), h1 = as_h2(hv2.y);
            const h16x2 h2 = as_h2(hv2.z), h3 = as_h2(hv2.w);
            a0 = dot2(w[0][8],  h0, a0); a1 = dot2(w[1][8],  h0, a1);
            a2 = dot2(w[2][8],  h0, a2); a3 = dot2(w[3][8],  h0, a3);
            a0 = dot2(w[0][9],  h1, a0); a1 = dot2(w[1][9],  h1, a1);
            a2 = dot2(w[2][9],  h1, a2); a3 = dot2(w[3][9],  h1, a3);
            a0 = dot2(w[0][10], h2, a0); a1 = dot2(w[1][10], h2, a1);
            a2 = dot2(w[2][10], h2, a2); a3 = dot2(w[3][10], h2, a3);
            a0 = dot2(w[0][11], h3, a0); a1 = dot2(w[1][11], h3, a1);
            a2 = dot2(w[2][11], h3, a2); a3 = dot2(w[3][11], h3, a3);
        }
        {
            const h16x2 h12 = as_h2(hv3);            // k = 25r+24 (+ zero pad)
            a0 = dot2(w[0][12], h12, a0); a1 = dot2(w[1][12], h12, a1);
            a2 = dot2(w[2][12], h12, a2); a3 = dot2(w[3][12], h12, a3);
        }
        // 2-level merge across the quad: all lanes end with full preacts
        a0 += QP(a0, DPP_XOR1); a1 += QP(a1, DPP_XOR1);
        a2 += QP(a2, DPP_XOR1); a3 += QP(a3, DPP_XOR1);
        a0 += QP(a0, DPP_XOR2); a1 += QP(a1, DPP_XOR2);
        a2 += QP(a2, DPP_XOR2); a3 += QP(a3, DPP_XOR2);

        // role r activates gate r (sig for 0,1,3; tanh for 2 via 2*sig(2s)-1)
        const float s   = (r & 2) ? ((r & 1) ? a3 : a2) : ((r & 1) ? a1 : a0);
        const float act = __builtin_fmaf(mm, RCPF(1.0f + __expf(-s * mm)), -mm1);

        // broadcast all four activations across the quad
        const float i_ = QP(act, DPP_BC0);
        const float f_ = QP(act, DPP_BC1);
        const float g_ = QP(act, DPP_BC2);
        const float o_ = QP(act, DPP_BC3);

        // uniform redundant cell update
        c = __builtin_fmaf(f_, c, i_ * g_);
        const float th   = __builtin_fmaf(-2.0f, RCPF(1.0f + __expf(2.0f * c)), 1.0f);
        const float hval = o_ * th;

        if (r == 0 && active)
            ((_Float16*)hbuf[wrb])[wslot] = (_Float16)hval;   // ds_write_b16
        __syncthreads();
    };

    const f32x2v* x2 = reinterpret_cast<const f32x2v*>(x);
    for (int t0 = 0; t0 < SEQLEN; t0 += XTILE) {
        reinterpret_cast<f32x2v*>(xsf)[tid] = x2[t0 * 2 + tid];  // 4 KB tile
        __syncthreads();
        for (int tt = 0; tt < XTILE; tt += 2) {
            step(0, 1, tt);      // even: read buf0, write buf1
            step(1, 0, tt + 1);  // odd:  read buf1, write buf0
        }
    }
    // after an even number of steps the current h is in hbuf[0]

    if (tid < HIDDEN) {
        const int slot = 32 * (tid / 25) + (tid % 25);
        red[tid] = (float)((const _Float16*)hbuf[0])[slot] * W_lin[tid];
    }
    __syncthreads();
    if (tid == 0) {
        float s = b_lin[0];
        for (int q = 0; q < HIDDEN; ++q) s += red[q];
        out[0] = s;
    }
}

extern "C" void kernel_launch(void* const* d_in, const int* in_sizes, int n_in,
                              void* d_out, int out_size, void* d_ws, size_t ws_size,
                              hipStream_t stream) {
    const float* x     = (const float*)d_in[0];
    const float* W_ih  = (const float*)d_in[1];
    const float* W_hh  = (const float*)d_in[2];
    const float* b_ih  = (const float*)d_in[3];
    const float* b_hh  = (const float*)d_in[4];
    const float* W_lin = (const float*)d_in[5];
    const float* b_lin = (const float*)d_in[6];
    float* out = (float*)d_out;

    lstm_seq9<<<dim3(1), dim3(NT), 0, stream>>>(
        x, W_ih, W_hh, b_ih, b_hh, W_lin, b_lin, out);
}

// Round 11
// 24514.262 us; speedup vs baseline: 1.1959x; 1.1959x over previous
//
#include <hip/hip_runtime.h>

#define HIDDEN  100
#define SEQLEN  65536
#define XTILE   256
#define NT      256   // 4 waves, one per SIMD

typedef float    f32x4 __attribute__((ext_vector_type(4)));
typedef _Float16 h16x2 __attribute__((ext_vector_type(2)));

#define DPP_XOR1 0xB1  // quad_perm [1,0,3,2]: lane <-> lane^1
#define DPP_XOR2 0x4E  // quad_perm [2,3,0,1]: lane <-> lane^2

#define LOG2E   1.44269504088896340736f
#define TWOL    2.88539008177792681472f   // 2*log2(e)

#if defined(__has_builtin) && __has_builtin(__builtin_amdgcn_rcpf)
#define RCPF(x) __builtin_amdgcn_rcpf(x)
#else
#define RCPF(x) (1.0f / (x))
#endif
#if defined(__has_builtin) && __has_builtin(__builtin_amdgcn_exp2f)
#define EXP2(x) __builtin_amdgcn_exp2f(x)   // raw v_exp_f32
#else
#define EXP2(x) exp2f(x)
#endif

#define QSWAP(v, ctrl) __int_as_float(__builtin_amdgcn_mov_dpp(__float_as_int(v), (ctrl), 0xf, 0xf, true))

static __device__ __forceinline__ h16x2 as_h2(unsigned u) {
    union { unsigned u; h16x2 h; } cv; cv.u = u; return cv.h;
}
static __device__ __forceinline__ unsigned pack_f16(float a, float b) {
#if defined(__has_builtin) && __has_builtin(__builtin_amdgcn_cvt_pkrtz)
    auto v = __builtin_amdgcn_cvt_pkrtz(a, b);
    union { decltype(v) h; unsigned u; } cv; cv.h = v;
    return cv.u;
#else
    union { h16x2 h; unsigned u; } cv;
    cv.h.x = (_Float16)a; cv.h.y = (_Float16)b;
    return cv.u;
#endif
}
static __device__ __forceinline__ float dot2(h16x2 a, h16x2 b, float c) {
#if defined(__has_builtin) && __has_builtin(__builtin_amdgcn_fdot2)
    return __builtin_amdgcn_fdot2(a, b, c, false);
#else
    return __builtin_fmaf((float)a.y, (float)b.y, __builtin_fmaf((float)a.x, (float)b.x, c));
#endif
}

// R9 structure (best: 24.85 ms) + exp2-folded weights + scaled-c tail.
// Lane pair (2j,2j+1) owns unit j; lane p computes K-half [50p,50p+50) for all
// 4 gate rows. Rows pre-scaled: i/f/o by -log2e, g by +2log2e, so sigmoid =
// rcp(1+exp2(s)) and tanh = fma(-2, rcp(1+exp2(s)), 1) with no lead-in mul.
// Cell kept as c2 = 2*log2e*c so tanh(c) also skips its mul.
// h LDS layout (f16): slots 0..49 = units 0..49 (dw 0..24), dw 25..27 pad;
// slots 56..105 = units 50..99 (dw 28..52).
__global__ __launch_bounds__(NT) __attribute__((amdgpu_waves_per_eu(1, 1)))
void lstm_seq10(const float* __restrict__ x,      // [SEQ][4]
                const float* __restrict__ W_ih,   // [400][4]
                const float* __restrict__ W_hh,   // [400][100]
                const float* __restrict__ b_ih,   // [400]
                const float* __restrict__ b_hh,   // [400]
                const float* __restrict__ W_lin,  // [1][100]
                const float* __restrict__ b_lin,  // [1]
                float* __restrict__ out)          // [1]
{
    __shared__ __align__(16) unsigned hbuf[2][64];
    __shared__ __align__(16) f32x4 xs[XTILE];
    __shared__ float red[112];

    const int tid = threadIdx.x;
    const int j   = tid >> 1;        // hidden unit (active < 100)
    const int p   = tid & 1;         // K-half / activation role
    const bool active = (j < HIDDEN);
    const int jj  = active ? j : 0;
    const int off = p * 50;          // K offset for this lane

    // ---- per-lane weights: 4 gate half-rows, 25 dwords each, pre-scaled ----
    h16x2 w[4][25];
    float wx0[4], wx1[4], bz[4];
#pragma unroll
    for (int g = 0; g < 4; ++g) {
        const float scale = (g == 2) ? TWOL : -LOG2E;   // fold exp2 conversion
        const int row = g * HIDDEN + jj;
        const float* wr = W_hh + row * HIDDEN + off;
#pragma unroll
        for (int q = 0; q < 25; ++q) {
            h16x2 pw;
            pw.x = (_Float16)(wr[2*q]   * scale);
            pw.y = (_Float16)(wr[2*q+1] * scale);
            w[g][q] = pw;
        }
        const f32x4 wih = reinterpret_cast<const f32x4*>(W_ih)[row];
        wx0[g] = (p ? wih.z : wih.x) * scale;
        wx1[g] = (p ? wih.w : wih.y) * scale;
        bz[g]  = p ? 0.f : ((b_ih[row] + b_hh[row]) * scale);
    }
    const float mm  = p ? -2.0f : 1.0f;  // p1 act0 = tanh: fma(-2, rcp, 1)
    const float cst = p ?  1.0f : 0.0f;  // p0 act0 = sigmoid: fma(1, rcp, 0)
    float c2 = 0.f;                      // 2*log2e * c; valid on p0 lanes

    if (tid < 64) { hbuf[0][tid] = 0u; hbuf[1][tid] = 0u; }
    __syncthreads();

    auto step = [&](const unsigned* hr, unsigned* hw, const f32x4 xv) {
        const unsigned* hb = hr + p * 28;
        const uint4* h4 = reinterpret_cast<const uint4*>(hb);
        uint4 hv[6];
#pragma unroll
        for (int t = 0; t < 6; ++t) hv[t] = h4[t];   // 6 ds_read_b128
        const unsigned hv6 = hb[24];                 // + 1 ds_read_b32

        const float xe0 = p ? xv.z : xv.x;
        const float xe1 = p ? xv.w : xv.y;
        float a0 = __builtin_fmaf(wx1[0], xe1, __builtin_fmaf(wx0[0], xe0, bz[0]));
        float a1 = __builtin_fmaf(wx1[1], xe1, __builtin_fmaf(wx0[1], xe0, bz[1]));
        float a2 = __builtin_fmaf(wx1[2], xe1, __builtin_fmaf(wx0[2], xe0, bz[2]));
        float a3 = __builtin_fmaf(wx1[3], xe1, __builtin_fmaf(wx0[3], xe0, bz[3]));
#pragma unroll
        for (int t = 0; t < 6; ++t) {
            const h16x2 h0 = as_h2(hv[t].x), h1 = as_h2(hv[t].y);
            const h16x2 h2 = as_h2(hv[t].z), h3 = as_h2(hv[t].w);
            a0 = dot2(w[0][4*t+0], h0, a0); a1 = dot2(w[1][4*t+0], h0, a1);
            a2 = dot2(w[2][4*t+0], h0, a2); a3 = dot2(w[3][4*t+0], h0, a3);
            a0 = dot2(w[0][4*t+1], h1, a0); a1 = dot2(w[1][4*t+1], h1, a1);
            a2 = dot2(w[2][4*t+1], h1, a2); a3 = dot2(w[3][4*t+1], h1, a3);
            a0 = dot2(w[0][4*t+2], h2, a0); a1 = dot2(w[1][4*t+2], h2, a1);
            a2 = dot2(w[2][4*t+2], h2, a2); a3 = dot2(w[3][4*t+2], h2, a3);
            a0 = dot2(w[0][4*t+3], h3, a0); a1 = dot2(w[1][4*t+3], h3, a1);
            a2 = dot2(w[2][4*t+3], h3, a2); a3 = dot2(w[3][4*t+3], h3, a3);
        }
        {
            const h16x2 h6 = as_h2(hv6);             // k = 48,49 / 98,99
            a0 = dot2(w[0][24], h6, a0); a1 = dot2(w[1][24], h6, a1);
            a2 = dot2(w[2][24], h6, a2); a3 = dot2(w[3][24], h6, a3);
        }
        // exchange only the halves each lane needs:
        //   p0 keeps gates {0,1} (i,f), sends its halves of {2,3};
        //   p1 keeps gates {2,3} (g,o), sends its halves of {0,1}.
        const float own0 = p ? a2 : a0, tx0 = p ? a0 : a2;
        const float own1 = p ? a3 : a1, tx1 = p ? a1 : a3;
        const float s0 = own0 + QSWAP(tx0, DPP_XOR1);
        const float s1 = own1 + QSWAP(tx1, DPP_XOR1);

        // act0: sigmoid(i) on p0 / tanh(g) on p1; act1: sigmoid(f / o)
        const float act0 = __builtin_fmaf(mm, RCPF(1.0f + EXP2(s0)), cst);
        const float act1 = RCPF(1.0f + EXP2(s1));

        const float g_ = QSWAP(act0, DPP_XOR1);   // p0 receives g
        const float o_ = QSWAP(act1, DPP_XOR1);   // p0 receives o
        const float i2 = act0 * TWOL;             // i * 2log2e (p0)

        // c2 = f*c2 + 2log2e*(i*g); tanh(c) = fma(-2, rcp(1+exp2(c2)), 1)
        c2 = __builtin_fmaf(act1, c2, i2 * g_);
        const float th   = __builtin_fmaf(-2.0f, RCPF(1.0f + EXP2(c2)), 1.0f);
        const float hval = o_ * th;

        // pack h pair (units 2m, 2m+1) in lane 4m and store one dword
        const float hoth = QSWAP(hval, DPP_XOR2);
        if ((tid & 3) == 0 && active) {
            const int m  = tid >> 2;               // pair index 0..49
            const int dw = (m < 25) ? m : m + 3;   // padded-slot dword
            hw[dw] = pack_f16(hval, hoth);
        }
        __syncthreads();
    };

    const f32x4* x4 = reinterpret_cast<const f32x4*>(x);
    for (int t0 = 0; t0 < SEQLEN; t0 += XTILE) {
        xs[tid] = x4[t0 + tid];
        __syncthreads();
        for (int tt = 0; tt < XTILE; tt += 2) {
            step(hbuf[0], hbuf[1], xs[tt]);      // even: read buf0, write buf1
            step(hbuf[1], hbuf[0], xs[tt + 1]);  // odd:  read buf1, write buf0
        }
    }
    // after an even number of steps the current h is in hbuf[0]

    if (tid < HIDDEN) {
        const int slot = (tid < 50) ? tid : tid + 6;
        const h16x2 hp = as_h2(hbuf[0][slot >> 1]);
        const float hj = (slot & 1) ? (float)hp.y : (float)hp.x;
        red[tid] = hj * W_lin[tid];
    }
    __syncthreads();
    if (tid == 0) {
        float s = b_lin[0];
        for (int q = 0; q < HIDDEN; ++q) s += red[q];
        out[0] = s;
    }
}

extern "C" void kernel_launch(void* const* d_in, const int* in_sizes, int n_in,
                              void* d_out, int out_size, void* d_ws, size_t ws_size,
                              hipStream_t stream) {
    const float* x     = (const float*)d_in[0];
    const float* W_ih  = (const float*)d_in[1];
    const float* W_hh  = (const float*)d_in[2];
    const float* b_ih  = (const float*)d_in[3];
    const float* b_hh  = (const float*)d_in[4];
    const float* W_lin = (const float*)d_in[5];
    const float* b_lin = (const float*)d_in[6];
    float* out = (float*)d_out;

    lstm_seq10<<<dim3(1), dim3(NT), 0, stream>>>(
        x, W_ih, W_hh, b_ih, b_hh, W_lin, b_lin, out);
}